// Round 3
// baseline (389.740 us; speedup 1.0000x reference)
//
#include <hip/hip_runtime.h>
#include <cmath>

#define B_      32
#define N_      4096
#define D_      512
#define D4      (D_/4)        // 128 float4 per row
#define NCH     32            // chunks per batch
#define RPC     128           // rows per chunk  (NCH*RPC == N_)
#define IN_DIM  1541          // 3*D + 5
#define NSPLIT  8             // layer-1 input-dim splits
#define CHUNK   193           // ceil(1541/8)
#define NEG_SENT (-1.0e8f)
#define BIGNEG   (1.0e30f)

// ---------------- Kernel 1: per-(batch,chunk) partial sum/sumsq/max ----------
// Measured-best v1 form: 128 thr x float4 column, single-pass ballot
// compaction. Only change vs the 381us baseline: unroll 4 -> 8
// (scheduling-only; per-column scalar accumulation chains are order-preserved,
// so bit-exact) to double in-flight loads at the 2-waves/SIMD occupancy.
__global__ __launch_bounds__(128) void stats_partial_kernel(
    const float* __restrict__ x, const float* __restrict__ mask,
    float4* __restrict__ psum, float4* __restrict__ psq,
    float4* __restrict__ pmax, float* __restrict__ pcnt)
{
    __shared__ int sidx[RPC];
    __shared__ int swc0, swc1;
    const int tx   = threadIdx.x;   // 0..127: float4 lane AND row slot
    const int wave = tx >> 6;
    const int lane = tx & 63;
    const int c    = blockIdx.x;    // chunk
    const int b    = blockIdx.y;    // batch

    {   // stable ballot compaction of valid rows
        const float mv = mask[b * N_ + c * RPC + tx];
        const bool pred = mv > NEG_SENT;
        const unsigned long long bal = __ballot(pred);
        const int prefix = __popcll(bal & ((1ull << lane) - 1ull));
        if (lane == 0) { if (wave == 0) swc0 = __popcll(bal); else swc1 = __popcll(bal); }
        __syncthreads();
        const int base = (wave == 0) ? 0 : swc0;
        if (pred) sidx[base + prefix] = tx;
    }
    __syncthreads();
    const int m = swc0 + swc1;
    if (tx == 0) pcnt[b * NCH + c] = (float)m;

    const float4* __restrict__ xb =
        (const float4*)x + ((size_t)b * N_ + (size_t)c * RPC) * D4 + tx;

    float4 s  = {0,0,0,0};
    float4 q  = {0,0,0,0};
    float4 mx = {-BIGNEG,-BIGNEG,-BIGNEG,-BIGNEG};

    #pragma unroll 8
    for (int i = 0; i < m; ++i) {
        const int r = sidx[i];
        const float4 v = xb[(size_t)r * D4];
        s.x += v.x; s.y += v.y; s.z += v.z; s.w += v.w;
        q.x = fmaf(v.x, v.x, q.x); q.y = fmaf(v.y, v.y, q.y);
        q.z = fmaf(v.z, v.z, q.z); q.w = fmaf(v.w, v.w, q.w);
        mx.x = fmaxf(mx.x, v.x); mx.y = fmaxf(mx.y, v.y);
        mx.z = fmaxf(mx.z, v.z); mx.w = fmaxf(mx.w, v.w);
    }

    const size_t idx = ((size_t)(b * NCH + c)) * D4 + tx;
    psum[idx] = s; psq[idx] = q; pmax[idx] = mx;
}

// ---------------- Kernel 2: combine partials -> g (LDS) -> layer-1 partials --
// Fusion of combine_g + layer1 (verified bit-exact in round 1: absmax 0.0):
// g never round-trips through HBM, one launch gap removed. All reduction /
// dot-product orders identical to the 381us baseline.
__global__ __launch_bounds__(256) void combine_layer1_kernel(
    const float4* __restrict__ psum, const float4* __restrict__ psq,
    const float4* __restrict__ pmax, const float* __restrict__ pcnt,
    const float* __restrict__ W1, float* __restrict__ h1p)
{
    __shared__ float4 Ss[2][D4], Sq[2][D4], Sm[2][D4];
    __shared__ float scnt;
    __shared__ float gsh[IN_DIM];

    const int tid = threadIdx.x;     // 0..255
    const int tx  = tid & 127;       // float4 lane
    const int ty  = tid >> 7;        // 0/1: which half of the chunks
    const int b   = blockIdx.x;

    {   // 2-way parallel chunk reduction (order identical to baseline)
        float4 s = {0,0,0,0}, q = {0,0,0,0};
        float4 mx = {-BIGNEG,-BIGNEG,-BIGNEG,-BIGNEG};
        const int c0 = ty * (NCH/2);
        #pragma unroll 4
        for (int c = c0; c < c0 + NCH/2; ++c) {
            const size_t idx = ((size_t)(b * NCH + c)) * D4 + tx;
            float4 a = psum[idx], u = psq[idx], w = pmax[idx];
            s.x += a.x; s.y += a.y; s.z += a.z; s.w += a.w;
            q.x += u.x; q.y += u.y; q.z += u.z; q.w += u.w;
            mx.x = fmaxf(mx.x,w.x); mx.y = fmaxf(mx.y,w.y);
            mx.z = fmaxf(mx.z,w.z); mx.w = fmaxf(mx.w,w.w);
        }
        Ss[ty][tx] = s; Sq[ty][tx] = q; Sm[ty][tx] = mx;
    }
    if (tid < NCH) {   // count reduction over 32 chunks (wave 0, same tree)
        float cv = pcnt[b * NCH + tid];
        #pragma unroll
        for (int off = 16; off > 0; off >>= 1) cv += __shfl_down(cv, off);
        if (tid == 0) scnt = cv;
    }
    __syncthreads();

    const float cnt = scnt;
    if (ty == 0) {   // merge halves, compute g into LDS
        float4 s = Ss[0][tx], s_ = Ss[1][tx];
        float4 q = Sq[0][tx], q_ = Sq[1][tx];
        float4 mx = Sm[0][tx], m_ = Sm[1][tx];
        s.x += s_.x; s.y += s_.y; s.z += s_.z; s.w += s_.w;
        q.x += q_.x; q.y += q_.y; q.z += q_.z; q.w += q_.w;
        mx.x = fmaxf(mx.x,m_.x); mx.y = fmaxf(mx.y,m_.y);
        mx.z = fmaxf(mx.z,m_.z); mx.w = fmaxf(mx.w,m_.w);

        const bool  has = cnt > 0.f;
        const float inv = 1.f / fmaxf(cnt, 1.f);
        const float dn  = 1.f / fmaxf(cnt - 1.f, 1.f);
        float sa[4] = {s.x,s.y,s.z,s.w};
        float qa[4] = {q.x,q.y,q.z,q.w};
        float ma[4] = {mx.x,mx.y,mx.z,mx.w};
        #pragma unroll
        for (int k = 0; k < 4; ++k) {
            const int d = 4*tx + k;
            const float mn = has ? sa[k] * inv : 0.f;
            const float vv = fmaxf((qa[k] - cnt * mn * mn) * dn, 0.f);
            gsh[d]        = mn;
            gsh[D_ + d]   = has ? ma[k] : 0.f;
            gsh[2*D_ + d] = has ? sqrtf(vv) : 0.f;
        }
        if (tx == 0) {
            gsh[3*D_ + 0] = logf(cnt + 1.f) * 0.2f;
            gsh[3*D_ + 1] = 0.1f;
            gsh[3*D_ + 2] = 0.2f;
            gsh[3*D_ + 3] = 4.0f;
            gsh[3*D_ + 4] = 0.1f;
        }
    }
    __syncthreads();

    {   // layer-1 partial dot products: thread (p, o) handles chunks {p, p+4}
        const int o = tid & 63;          // output unit
        const int p = tid >> 6;          // 0..3
        #pragma unroll
        for (int cc = 0; cc < 2; ++cc) {
            const int c  = p + cc * 4;
            const int i0 = c * CHUNK;
            const int len = (IN_DIM - i0) < CHUNK ? (IN_DIM - i0) : CHUNK;
            const float* __restrict__ Wp = W1 + (size_t)i0 * 64 + o;
            float a = 0.f;
            #pragma unroll 8
            for (int k = 0; k < len; ++k)
                a = fmaf(gsh[i0 + k], Wp[(size_t)k * 64], a);
            h1p[((size_t)b * NSPLIT + c) * 64 + o] = a;
        }
    }
}

// ---------------- Kernel 3: finish — reduce partials, L2, L3, output --------
__global__ __launch_bounds__(1024) void finish_kernel(
    const float* __restrict__ h1p, const float* __restrict__ b1,
    const float* __restrict__ W2, const float* __restrict__ b2,
    const float* __restrict__ W3, const float* __restrict__ b3,
    float* __restrict__ out)
{
    __shared__ float h1s[B_ * 64];    // 8 KB
    __shared__ float h2s[B_ * 33];    // padded stride 33: no bank conflicts
    const int tid = threadIdx.x;      // 0..1023

    #pragma unroll
    for (int r = 0; r < 2; ++r) {     // layer-1 reduce+bias+relu: 2048 outputs
        const int oi = tid + r * 1024;   // b*64+o
        const int b = oi >> 6, o = oi & 63;
        float a = b1[o];
        #pragma unroll
        for (int c = 0; c < NSPLIT; ++c) a += h1p[((size_t)b * NSPLIT + c) * 64 + o];
        h1s[oi] = fmaxf(a, 0.f);
    }
    __syncthreads();

    {   // layer 2: 32 batches x 32 outputs, one thread each
        const int b = tid >> 5, o = tid & 31;
        float a = b2[o];
        #pragma unroll
        for (int i = 0; i < 64; ++i) a = fmaf(h1s[b*64 + i], W2[i*32 + o], a);
        h2s[b*33 + o] = fmaxf(a, 0.f);
    }
    __syncthreads();

    if (tid < 32) {   // layer 3 + sigmoid + final reduction (all in wave 0)
        const int b = tid;
        float a = b3[0];
        #pragma unroll
        for (int i = 0; i < 32; ++i) a = fmaf(h2s[b*33 + i], W3[i], a);
        float sc = 1.f / (1.f + expf(-a));
        float r  = rintf(3.f + sc * 47.f);   // rintf == round-half-even == jnp.round
        #pragma unroll
        for (int off = 16; off > 0; off >>= 1) {
            sc += __shfl_down(sc, off);
            r  += __shfl_down(r,  off);
        }
        if (tid == 0) {
            const float mean_r = r * (1.f / 32.f);   // exact: sum of ints / 2^5
            int nc = (int)mean_r;                    // astype(int32): trunc toward 0
            nc = nc < 3 ? 3 : (nc > 50 ? 50 : nc);
            out[0] = (float)nc;
            out[1] = sc * (1.f / 32.f);
        }
    }
}

extern "C" void kernel_launch(void* const* d_in, const int* in_sizes, int n_in,
                              void* d_out, int out_size, void* d_ws, size_t ws_size,
                              hipStream_t stream)
{
    const float* x    = (const float*)d_in[0];
    const float* mask = (const float*)d_in[1];
    const float* W1   = (const float*)d_in[2];
    const float* b1   = (const float*)d_in[3];
    const float* W2   = (const float*)d_in[4];
    const float* b2   = (const float*)d_in[5];
    const float* W3   = (const float*)d_in[6];
    const float* b3   = (const float*)d_in[7];
    float* out = (float*)d_out;

    // ws: psum|psq|pmax (2 MiB each) | pcnt | h1p
    const size_t PCOUNT = (size_t)B_ * NCH * D4;      // 131072 float4 per array
    float4* psum = (float4*)d_ws;
    float4* psq  = psum + PCOUNT;
    float4* pmax = psq  + PCOUNT;
    float*  pcnt = (float*)(pmax + PCOUNT);           // B_*NCH floats
    float*  h1p  = pcnt + (size_t)B_ * NCH;           // B_*NSPLIT*64 floats

    dim3 gridA(NCH, B_);
    stats_partial_kernel<<<gridA, 128, 0, stream>>>(x, mask, psum, psq, pmax, pcnt);
    combine_layer1_kernel<<<B_, 256, 0, stream>>>(psum, psq, pmax, pcnt, W1, h1p);
    finish_kernel<<<1, 1024, 0, stream>>>(h1p, b1, W2, b2, W3, b3, out);
}

// Round 4
// 379.387 us; speedup vs baseline: 1.0273x; 1.0273x over previous
//
#include <hip/hip_runtime.h>
#include <cmath>

#define B_      32
#define N_      4096
#define D_      512
#define D4      (D_/4)        // 128 float4 per row
#define NCH     32            // chunks per batch
#define RPC     128           // rows per chunk  (NCH*RPC == N_)
#define IN_DIM  1541          // 3*D + 5
#define GSTRIDE 1568          // padded g row stride
#define NSPLIT  8             // layer-1 input-dim splits
#define CHUNK   193           // ceil(1541/8)
#define NEG_SENT (-1.0e8f)
#define BIGNEG   (1.0e30f)

// ---------------- Kernel 1: per-(batch,chunk) partial sum/sumsq/max ----------
// Valid-row skip: ballot-compacted row indices (stable order => bit-identical
// sums vs streaming-with-zero-weight), ~25% fewer HBM bytes. 1024 blocks x
// 128 thr, 16 waves/CU hide the ds_read->global_load index chain.
// NOTE: measured-best configuration (381 us). unroll 8 (R3: 389.7) and
// float2 split (R1: 387.2) both regressed — do not re-apply.
__global__ __launch_bounds__(128) void stats_partial_kernel(
    const float* __restrict__ x, const float* __restrict__ mask,
    float4* __restrict__ psum, float4* __restrict__ psq,
    float4* __restrict__ pmax, float* __restrict__ pcnt)
{
    __shared__ int sidx[RPC];
    __shared__ int swc0, swc1;
    const int tx   = threadIdx.x;   // 0..127: float4 lane AND row slot
    const int wave = tx >> 6;
    const int lane = tx & 63;
    const int c    = blockIdx.x;    // chunk
    const int b    = blockIdx.y;    // batch

    {   // stable ballot compaction of valid rows
        const float mv = mask[b * N_ + c * RPC + tx];
        const bool pred = mv > NEG_SENT;
        const unsigned long long bal = __ballot(pred);
        const int prefix = __popcll(bal & ((1ull << lane) - 1ull));
        if (lane == 0) { if (wave == 0) swc0 = __popcll(bal); else swc1 = __popcll(bal); }
        __syncthreads();
        const int base = (wave == 0) ? 0 : swc0;
        if (pred) sidx[base + prefix] = tx;
    }
    __syncthreads();
    const int m = swc0 + swc1;
    if (tx == 0) pcnt[b * NCH + c] = (float)m;

    const float4* __restrict__ xb =
        (const float4*)x + ((size_t)b * N_ + (size_t)c * RPC) * D4 + tx;

    float4 s  = {0,0,0,0};
    float4 q  = {0,0,0,0};
    float4 mx = {-BIGNEG,-BIGNEG,-BIGNEG,-BIGNEG};

    #pragma unroll 4
    for (int i = 0; i < m; ++i) {
        const int r = sidx[i];
        const float4 v = xb[(size_t)r * D4];
        s.x += v.x; s.y += v.y; s.z += v.z; s.w += v.w;
        q.x = fmaf(v.x, v.x, q.x); q.y = fmaf(v.y, v.y, q.y);
        q.z = fmaf(v.z, v.z, q.z); q.w = fmaf(v.w, v.w, q.w);
        mx.x = fmaxf(mx.x, v.x); mx.y = fmaxf(mx.y, v.y);
        mx.z = fmaxf(mx.z, v.z); mx.w = fmaxf(mx.w, v.w);
    }

    const size_t idx = ((size_t)(b * NCH + c)) * D4 + tx;
    psum[idx] = s; psq[idx] = q; pmax[idx] = mx;
}

// ---------------- Kernel 2: combine partials -> g (global) ------------------
__global__ __launch_bounds__(256) void combine_g_kernel(
    const float4* __restrict__ psum, const float4* __restrict__ psq,
    const float4* __restrict__ pmax, const float* __restrict__ pcnt,
    float* __restrict__ g_all)
{
    __shared__ float4 Ss[2][D4], Sq[2][D4], Sm[2][D4];
    __shared__ float scnt;

    const int tid = threadIdx.x;     // 0..255
    const int tx  = tid & 127;       // float4 lane
    const int ty  = tid >> 7;        // 0/1: which half of the chunks
    const int b   = blockIdx.x;

    {   // 2-way parallel chunk reduction
        float4 s = {0,0,0,0}, q = {0,0,0,0};
        float4 mx = {-BIGNEG,-BIGNEG,-BIGNEG,-BIGNEG};
        const int c0 = ty * (NCH/2);
        #pragma unroll 4
        for (int c = c0; c < c0 + NCH/2; ++c) {
            const size_t idx = ((size_t)(b * NCH + c)) * D4 + tx;
            float4 a = psum[idx], u = psq[idx], w = pmax[idx];
            s.x += a.x; s.y += a.y; s.z += a.z; s.w += a.w;
            q.x += u.x; q.y += u.y; q.z += u.z; q.w += u.w;
            mx.x = fmaxf(mx.x,w.x); mx.y = fmaxf(mx.y,w.y);
            mx.z = fmaxf(mx.z,w.z); mx.w = fmaxf(mx.w,w.w);
        }
        Ss[ty][tx] = s; Sq[ty][tx] = q; Sm[ty][tx] = mx;
    }
    if (tid < NCH) {   // count reduction over 32 chunks (wave 0)
        float cv = pcnt[b * NCH + tid];
        #pragma unroll
        for (int off = 16; off > 0; off >>= 1) cv += __shfl_down(cv, off);
        if (tid == 0) scnt = cv;
    }
    __syncthreads();

    const float cnt = scnt;
    float* __restrict__ g = g_all + (size_t)b * GSTRIDE;
    if (ty == 0) {   // merge halves, compute g
        float4 s = Ss[0][tx], s_ = Ss[1][tx];
        float4 q = Sq[0][tx], q_ = Sq[1][tx];
        float4 mx = Sm[0][tx], m_ = Sm[1][tx];
        s.x += s_.x; s.y += s_.y; s.z += s_.z; s.w += s_.w;
        q.x += q_.x; q.y += q_.y; q.z += q_.z; q.w += q_.w;
        mx.x = fmaxf(mx.x,m_.x); mx.y = fmaxf(mx.y,m_.y);
        mx.z = fmaxf(mx.z,m_.z); mx.w = fmaxf(mx.w,m_.w);

        const bool  has = cnt > 0.f;
        const float inv = 1.f / fmaxf(cnt, 1.f);
        const float dn  = 1.f / fmaxf(cnt - 1.f, 1.f);
        float sa[4] = {s.x,s.y,s.z,s.w};
        float qa[4] = {q.x,q.y,q.z,q.w};
        float ma[4] = {mx.x,mx.y,mx.z,mx.w};
        #pragma unroll
        for (int k = 0; k < 4; ++k) {
            const int d = 4*tx + k;
            const float mn = has ? sa[k] * inv : 0.f;
            const float vv = fmaxf((qa[k] - cnt * mn * mn) * dn, 0.f);
            g[d]        = mn;
            g[D_ + d]   = has ? ma[k] : 0.f;
            g[2*D_ + d] = has ? sqrtf(vv) : 0.f;
        }
        if (tx == 0) {
            g[3*D_ + 0] = logf(cnt + 1.f) * 0.2f;
            g[3*D_ + 1] = 0.1f;
            g[3*D_ + 2] = 0.2f;
            g[3*D_ + 3] = 4.0f;
            g[3*D_ + 4] = 0.1f;
        }
    }
}

// ---------------- Kernel 3: layer-1 partial dot products --------------------
// 8 i-chunks x 32 batches = 256 blocks x 64 threads.
__global__ __launch_bounds__(64) void layer1_kernel(
    const float* __restrict__ g_all, const float* __restrict__ W1,
    float* __restrict__ h1p)
{
    __shared__ float sg[CHUNK];
    const int o  = threadIdx.x;          // 0..63 output unit
    const int c  = blockIdx.x;           // 0..7 input chunk
    const int b  = blockIdx.y;           // batch
    const int i0 = c * CHUNK;
    const int len = (IN_DIM - i0) < CHUNK ? (IN_DIM - i0) : CHUNK;

    for (int j = o; j < len; j += 64) sg[j] = g_all[(size_t)b * GSTRIDE + i0 + j];
    __syncthreads();

    const float* __restrict__ Wp = W1 + (size_t)i0 * 64 + o;
    float a = 0.f;
    #pragma unroll 8
    for (int k = 0; k < len; ++k)
        a = fmaf(sg[k], Wp[(size_t)k * 64], a);
    h1p[((size_t)b * NSPLIT + c) * 64 + o] = a;
}

// ---------------- Kernel 4: finish — reduce partials, L2, L3, output --------
__global__ __launch_bounds__(1024) void finish_kernel(
    const float* __restrict__ h1p, const float* __restrict__ b1,
    const float* __restrict__ W2, const float* __restrict__ b2,
    const float* __restrict__ W3, const float* __restrict__ b3,
    float* __restrict__ out)
{
    __shared__ float h1s[B_ * 64];    // 8 KB
    __shared__ float h2s[B_ * 33];    // padded stride 33: no bank conflicts
    const int tid = threadIdx.x;      // 0..1023

    #pragma unroll
    for (int r = 0; r < 2; ++r) {     // layer-1 reduce+bias+relu: 2048 outputs
        const int oi = tid + r * 1024;   // b*64+o
        const int b = oi >> 6, o = oi & 63;
        float a = b1[o];
        #pragma unroll
        for (int c = 0; c < NSPLIT; ++c) a += h1p[((size_t)b * NSPLIT + c) * 64 + o];
        h1s[oi] = fmaxf(a, 0.f);
    }
    __syncthreads();

    {   // layer 2: 32 batches x 32 outputs, one thread each
        const int b = tid >> 5, o = tid & 31;
        float a = b2[o];
        #pragma unroll
        for (int i = 0; i < 64; ++i) a = fmaf(h1s[b*64 + i], W2[i*32 + o], a);
        h2s[b*33 + o] = fmaxf(a, 0.f);
    }
    __syncthreads();

    if (tid < 32) {   // layer 3 + sigmoid + final reduction (all in wave 0)
        const int b = tid;
        float a = b3[0];
        #pragma unroll
        for (int i = 0; i < 32; ++i) a = fmaf(h2s[b*33 + i], W3[i], a);
        float sc = 1.f / (1.f + expf(-a));
        float r  = rintf(3.f + sc * 47.f);   // rintf == round-half-even == jnp.round
        #pragma unroll
        for (int off = 16; off > 0; off >>= 1) {
            sc += __shfl_down(sc, off);
            r  += __shfl_down(r,  off);
        }
        if (tid == 0) {
            const float mean_r = r * (1.f / 32.f);   // exact: sum of ints / 2^5
            int nc = (int)mean_r;                    // astype(int32): trunc toward 0
            nc = nc < 3 ? 3 : (nc > 50 ? 50 : nc);
            out[0] = (float)nc;
            out[1] = sc * (1.f / 32.f);
        }
    }
}

extern "C" void kernel_launch(void* const* d_in, const int* in_sizes, int n_in,
                              void* d_out, int out_size, void* d_ws, size_t ws_size,
                              hipStream_t stream)
{
    const float* x    = (const float*)d_in[0];
    const float* mask = (const float*)d_in[1];
    const float* W1   = (const float*)d_in[2];
    const float* b1   = (const float*)d_in[3];
    const float* W2   = (const float*)d_in[4];
    const float* b2   = (const float*)d_in[5];
    const float* W3   = (const float*)d_in[6];
    const float* b3   = (const float*)d_in[7];
    float* out = (float*)d_out;

    // ws: psum|psq|pmax (2 MiB each) | pcnt | g_all (200 KB) | h1p (64 KB)
    const size_t PCOUNT = (size_t)B_ * NCH * D4;      // 131072 float4 per array
    float4* psum = (float4*)d_ws;
    float4* psq  = psum + PCOUNT;
    float4* pmax = psq  + PCOUNT;
    float*  pcnt = (float*)(pmax + PCOUNT);           // B_*NCH floats
    float*  g_all = pcnt + (size_t)B_ * NCH;          // B_*GSTRIDE floats
    float*  h1p   = g_all + (size_t)B_ * GSTRIDE;     // B_*NSPLIT*64 floats

    dim3 gridA(NCH, B_);
    stats_partial_kernel<<<gridA, 128, 0, stream>>>(x, mask, psum, psq, pmax, pcnt);
    combine_g_kernel<<<B_, 256, 0, stream>>>(psum, psq, pmax, pcnt, g_all);
    dim3 gridL1(NSPLIT, B_);
    layer1_kernel<<<gridL1, 64, 0, stream>>>(g_all, W1, h1p);
    finish_kernel<<<1, 1024, 0, stream>>>(h1p, b1, W2, b2, W3, b3, out);
}